// Round 2
// baseline (447.001 us; speedup 1.0000x reference)
//
#include <hip/hip_runtime.h>
#include <hip/hip_bf16.h>
#include <math.h>

#define DIM 256          // D_IN == EMBED == 256
#define HEADS 8
#define HEAD_DIM 32

// ---------------------------------------------------------------------------
// Projection GEMM: P = nodes @ W + b   (M x 256) = (M x 256)(256 x 256)
// Block: 512 threads, tile 64 rows x 256 cols. Each thread: 8 rows x 4 cols.
// A tile staged in LDS (64KB, wave-uniform broadcast reads); W through L2.
// float2-packed accumulators to allow v_pk_fma_f32 formation.
// ---------------------------------------------------------------------------
__global__ __launch_bounds__(512, 4) void proj_kernel(
    const float* __restrict__ nodes, const float* __restrict__ W,
    const float* __restrict__ b, float* __restrict__ P, int M) {
  __shared__ float A[64][DIM];  // 64 KiB
  const int t = threadIdx.x;
  const int row0 = blockIdx.x * 64;

  // cooperative tile load, float4-vectorized, coalesced
  const float4* n4 = (const float4*)nodes;       // row stride 64 float4
  float4* A4 = (float4*)(&A[0][0]);
  #pragma unroll
  for (int i = 0; i < 8; ++i) {
    int u = t + i * 512;                          // 0..4095
    int r = u >> 6, q = u & 63;
    int gr = row0 + r;
    float4 v = make_float4(0.f, 0.f, 0.f, 0.f);
    if (gr < M) v = n4[gr * 64 + q];
    A4[u] = v;
  }
  __syncthreads();

  const int tx = t & 63;    // column lane: cols {tx, tx+64, tx+128, tx+192}
  const int ty = t >> 6;    // wave id: rows ty*8 .. ty*8+7

  float2 acc[8][2];
  #pragma unroll
  for (int r = 0; r < 8; ++r) {
    acc[r][0] = make_float2(0.f, 0.f);
    acc[r][1] = make_float2(0.f, 0.f);
  }

  for (int k4 = 0; k4 < 64; ++k4) {
    float2 w[4][2];
    #pragma unroll
    for (int i = 0; i < 4; ++i) {
      const float* Wr = W + (k4 * 4 + i) * DIM;
      w[i][0] = make_float2(Wr[tx], Wr[tx + 64]);
      w[i][1] = make_float2(Wr[tx + 128], Wr[tx + 192]);
    }
    #pragma unroll
    for (int r = 0; r < 8; ++r) {
      float4 a = A4[(ty * 8 + r) * 64 + k4];      // LDS broadcast (uniform addr)
      #pragma unroll
      for (int p = 0; p < 2; ++p) {
        acc[r][p].x += a.x * w[0][p].x; acc[r][p].y += a.x * w[0][p].y;
        acc[r][p].x += a.y * w[1][p].x; acc[r][p].y += a.y * w[1][p].y;
        acc[r][p].x += a.z * w[2][p].x; acc[r][p].y += a.z * w[2][p].y;
        acc[r][p].x += a.w * w[3][p].x; acc[r][p].y += a.w * w[3][p].y;
      }
    }
  }

  const float b0 = b[tx], b1 = b[tx + 64], b2 = b[tx + 128], b3 = b[tx + 192];
  #pragma unroll
  for (int r = 0; r < 8; ++r) {
    int gr = row0 + ty * 8 + r;
    if (gr < M) {
      float* o = P + gr * DIM;
      o[tx]       = acc[r][0].x + b0;
      o[tx + 64]  = acc[r][0].y + b1;
      o[tx + 128] = acc[r][1].x + b2;
      o[tx + 192] = acc[r][1].y + b3;
    }
  }
}

// ---------------------------------------------------------------------------
// CSR build: histogram -> hierarchical scan (A/B/C) -> scatter
// ---------------------------------------------------------------------------
__global__ void hist_kernel(const int* __restrict__ recv, int* __restrict__ cnt,
                            int E) {
  int e = blockIdx.x * 256 + threadIdx.x;
  if (e < E) atomicAdd(&cnt[recv[e]], 1);
}

// inclusive scan of x across a 256-thread block (4 waves)
__device__ __forceinline__ int block_scan256(int x, int t, int* wsum) {
  const int lane = t & 63, wid = t >> 6;
  #pragma unroll
  for (int d = 1; d < 64; d <<= 1) {
    int y = __shfl_up(x, (unsigned)d);
    if (lane >= d) x += y;
  }
  if (lane == 63) wsum[wid] = x;
  __syncthreads();
  int add = 0;
  if (wid > 0) add += wsum[0];
  if (wid > 1) add += wsum[1];
  if (wid > 2) add += wsum[2];
  x += add;
  __syncthreads();  // wsum may be reused by caller loops
  return x;
}

// A: per-256-block inclusive scan of cnt -> offs[i+1] (partial), block sums
__global__ __launch_bounds__(256) void scanA_kernel(const int* __restrict__ cnt,
                                                    int* __restrict__ offs,
                                                    int* __restrict__ bsum,
                                                    int n) {
  __shared__ int wsum[4];
  const int t = threadIdx.x;
  const int i = blockIdx.x * 256 + t;
  int x = (i < n) ? cnt[i] : 0;
  int s = block_scan256(x, t, wsum);
  if (i < n) offs[i + 1] = s;
  if (t == 255) bsum[blockIdx.x] = s;
  if (t == 0 && blockIdx.x == 0) offs[0] = 0;
}

// B: single block scans the block sums -> exclusive bases
__global__ __launch_bounds__(256) void scanB_kernel(const int* __restrict__ bsum,
                                                    int* __restrict__ bbase,
                                                    int nb) {
  __shared__ int wsum[4];
  __shared__ int carry_s;
  const int t = threadIdx.x;
  if (t == 0) carry_s = 0;
  __syncthreads();
  for (int base = 0; base < nb; base += 256) {
    int i = base + t;
    int x = (i < nb) ? bsum[i] : 0;
    int s = block_scan256(x, t, wsum);
    int c = carry_s;
    if (i < nb) bbase[i] = c + s - x;  // exclusive base
    __syncthreads();
    if (t == 255) carry_s = c + s;     // s at t==255 == chunk total
    __syncthreads();
  }
}

// C: add block bases
__global__ __launch_bounds__(256) void scanC_kernel(int* __restrict__ offs,
                                                    const int* __restrict__ bbase,
                                                    int n) {
  const int i = blockIdx.x * 256 + threadIdx.x;
  if (i < n) offs[i + 1] += bbase[blockIdx.x];
}

__global__ void scatter_kernel(const int* __restrict__ recv,
                               const int* __restrict__ snd,
                               const int* __restrict__ offs,
                               int* __restrict__ cursor,
                               int* __restrict__ sorted_snd, int E) {
  int e = blockIdx.x * 256 + threadIdx.x;
  if (e < E) {
    int r = recv[e];
    int slot = offs[r] + atomicAdd(&cursor[r], 1);
    sorted_snd[slot] = snd[e];
  }
}

// ---------------------------------------------------------------------------
// Fused per-node kernel: one wave per receiver node.
// lane owns value-quad v = 4*lane..4*lane+3 (head h = lane/8).
// Online softmax across incoming edges; no atomics, no logits materialized.
// 1-deep software pipeline on the Pi gather.
// ---------------------------------------------------------------------------
__device__ __forceinline__ float mish_f(float x) {
  // mish(x) = x * tanh(softplus(x)) = x * u/(u+2), u = t(t+2), t = e^x
  float t = __expf(fminf(x, 40.f));
  float u = t * (t + 2.f);
  return x * u * __builtin_amdgcn_rcpf(u + 2.f);
}

__global__ __launch_bounds__(256) void node_kernel(
    const float* __restrict__ Pi, const float* __restrict__ Pj,
    const int* __restrict__ offs, const int* __restrict__ sorted_snd,
    const float* __restrict__ a_w, const float* __restrict__ a_b,
    float* __restrict__ out, int n) {
  const int wid = threadIdx.x >> 6, lane = threadIdx.x & 63;
  const int r = blockIdx.x * 4 + wid;
  if (r >= n) return;

  const int beg = offs[r], end = offs[r + 1];
  const float4* Pi4 = (const float4*)Pi;
  const float4* Pj4 = (const float4*)Pj;

  const float4 pj = Pj4[r * 64 + lane];
  const float4 aw = ((const float4*)a_w)[lane & 7];  // a_w index = (4*lane+i)%32
  const float ab = a_b[0];

  float4 acc = make_float4(0.f, 0.f, 0.f, 0.f);
  float m = -INFINITY, denom = 0.f;

  float4 pi_next = make_float4(0.f, 0.f, 0.f, 0.f);
  if (beg < end) pi_next = Pi4[(size_t)sorted_snd[beg] * 64 + lane];

  for (int idx = beg; idx < end; ++idx) {
    float4 pi = pi_next;
    if (idx + 1 < end)
      pi_next = Pi4[(size_t)sorted_snd[idx + 1] * 64 + lane];  // prefetch

    float partial;
    partial  = mish_f(pi.x + pj.x) * aw.x;
    partial += mish_f(pi.y + pj.y) * aw.y;
    partial += mish_f(pi.z + pj.z) * aw.z;
    partial += mish_f(pi.w + pj.w) * aw.w;
    // reduce over the 8 lanes sharing this head
    partial += __shfl_xor(partial, 1);
    partial += __shfl_xor(partial, 2);
    partial += __shfl_xor(partial, 4);

    float lo = partial + ab;
    float mn = fmaxf(m, lo);
    float scale = __expf(m - mn);            // first iter: exp(-inf)=0
    float p = __expf(lo - mn);
    denom = denom * scale + p;
    acc.x = acc.x * scale + p * pi.x;
    acc.y = acc.y * scale + p * pi.y;
    acc.z = acc.z * scale + p * pi.z;
    acc.w = acc.w * scale + p * pi.w;
    m = mn;
  }

  float inv = (end > beg) ? 1.f / denom : 0.f;
  float4 o = make_float4(acc.x * inv, acc.y * inv, acc.z * inv, acc.w * inv);
  ((float4*)out)[r * 64 + lane] = o;
}

// ---------------------------------------------------------------------------
extern "C" void kernel_launch(void* const* d_in, const int* in_sizes, int n_in,
                              void* d_out, int out_size, void* d_ws,
                              size_t ws_size, hipStream_t stream) {
  const float* nodes = (const float*)d_in[0];
  const int* senders = (const int*)d_in[1];
  const int* receivers = (const int*)d_in[2];
  const float* Wi = (const float*)d_in[3];
  const float* bi = (const float*)d_in[4];
  const float* Wj = (const float*)d_in[5];
  const float* bj = (const float*)d_in[6];
  const float* a_w = (const float*)d_in[7];
  const float* a_b = (const float*)d_in[8];
  float* out = (float*)d_out;

  const int N = in_sizes[0] / DIM;
  const int E = in_sizes[1];
  const int nb = (N + 255) / 256;  // scan blocks

  // workspace layout
  char* ws = (char*)d_ws;
  float* Pi = (float*)ws;                         // N*256 f32
  float* Pj = Pi + (size_t)N * DIM;               // N*256 f32
  int* cnt = (int*)(Pj + (size_t)N * DIM);        // N
  int* cursor = cnt + N;                          // N   (contiguous with cnt)
  int* offs = cursor + N;                         // N+1
  int* bsum = offs + N + 1;                       // nb
  int* bbase = bsum + nb;                         // nb
  int* sorted_snd = bbase + nb;                   // E

  // zero histogram + cursor in one memset
  hipMemsetAsync(cnt, 0, (size_t)2 * N * sizeof(int), stream);

  const int projBlocks = (N + 63) / 64;
  proj_kernel<<<projBlocks, 512, 0, stream>>>(nodes, Wi, bi, Pi, N);
  proj_kernel<<<projBlocks, 512, 0, stream>>>(nodes, Wj, bj, Pj, N);

  hist_kernel<<<(E + 255) / 256, 256, 0, stream>>>(receivers, cnt, E);
  scanA_kernel<<<nb, 256, 0, stream>>>(cnt, offs, bsum, N);
  scanB_kernel<<<1, 256, 0, stream>>>(bsum, bbase, nb);
  scanC_kernel<<<nb, 256, 0, stream>>>(offs, bbase, N);
  scatter_kernel<<<(E + 255) / 256, 256, 0, stream>>>(receivers, senders, offs,
                                                      cursor, sorted_snd, E);

  node_kernel<<<(N + 3) / 4, 256, 0, stream>>>(Pi, Pj, offs, sorted_snd, a_w,
                                               a_b, out, N);
}

// Round 4
// 405.236 us; speedup vs baseline: 1.1031x; 1.1031x over previous
//
#include <hip/hip_runtime.h>
#include <hip/hip_bf16.h>
#include <math.h>

#define DIM 256          // D_IN == EMBED == 256
#define HEADS 8
#define HEAD_DIM 32

// ---------------------------------------------------------------------------
// Fused dual projection GEMM: Pi = nodes @ Wi + bi ; Pj = nodes @ Wj + bj
// Tile: 32 rows x 256 cols, 256 threads, 32 KiB LDS -> 5 blocks/CU (62% occ).
// Thread owns 4 CONTIGUOUS cols (4*tx..4*tx+3): W loads are coalesced float4,
// stores are float4. 1-deep register prefetch on W rows hides L1/L2 latency.
// Each thread: 8 rows x 4 cols per pass.
// ---------------------------------------------------------------------------
__device__ __forceinline__ void fma4(float4& acc, float s, const float4& w) {
  acc.x += s * w.x; acc.y += s * w.y; acc.z += s * w.z; acc.w += s * w.w;
}

__global__ __launch_bounds__(256, 5) void proj2_kernel(
    const float* __restrict__ nodes,
    const float* __restrict__ Wi, const float* __restrict__ bi,
    const float* __restrict__ Wj, const float* __restrict__ bj,
    float* __restrict__ Pi, float* __restrict__ Pj, int M) {
  __shared__ float A[32][DIM];  // 32 KiB
  const int t = threadIdx.x;
  const int row0 = blockIdx.x * 32;

  // cooperative tile load: 32*64 = 2048 float4, 8 per thread, coalesced
  const float4* n4 = (const float4*)nodes;
  float4* A4 = (float4*)(&A[0][0]);
  #pragma unroll
  for (int i = 0; i < 8; ++i) {
    int u = t + i * 256;                     // 0..2047
    int r = u >> 6, q = u & 63;
    int gr = row0 + r;
    float4 v = make_float4(0.f, 0.f, 0.f, 0.f);
    if (gr < M) v = n4[(size_t)gr * 64 + q];
    A4[u] = v;
  }
  __syncthreads();

  const int tx = t & 63;    // col quad: cols 4*tx .. 4*tx+3
  const int ty = t >> 6;    // wave id: rows ty*8 .. ty*8+7

  #pragma unroll
  for (int pass = 0; pass < 2; ++pass) {
    const float4* W4 = (const float4*)(pass ? Wj : Wi);  // row stride 64 float4
    const float4* b4 = (const float4*)(pass ? bj : bi);
    float* P = pass ? Pj : Pi;

    float4 acc[8];
    #pragma unroll
    for (int r = 0; r < 8; ++r) acc[r] = make_float4(0.f, 0.f, 0.f, 0.f);

    // prefetch k4 = 0
    float4 wn0 = W4[0 * 64 + tx];
    float4 wn1 = W4[1 * 64 + tx];
    float4 wn2 = W4[2 * 64 + tx];
    float4 wn3 = W4[3 * 64 + tx];

    for (int k4 = 0; k4 < 64; ++k4) {
      float4 w0 = wn0, w1 = wn1, w2 = wn2, w3 = wn3;
      int kn = (k4 + 1) & 63;                // last iter reloads row 0: harmless
      wn0 = W4[(kn * 4 + 0) * 64 + tx];
      wn1 = W4[(kn * 4 + 1) * 64 + tx];
      wn2 = W4[(kn * 4 + 2) * 64 + tx];
      wn3 = W4[(kn * 4 + 3) * 64 + tx];
      #pragma unroll
      for (int r = 0; r < 8; ++r) {
        float4 a = A4[(ty * 8 + r) * 64 + k4];  // wave-uniform LDS broadcast
        fma4(acc[r], a.x, w0);
        fma4(acc[r], a.y, w1);
        fma4(acc[r], a.z, w2);
        fma4(acc[r], a.w, w3);
      }
    }

    const float4 bv = b4[tx];
    #pragma unroll
    for (int r = 0; r < 8; ++r) {
      int gr = row0 + ty * 8 + r;
      if (gr < M) {
        float4 o = make_float4(acc[r].x + bv.x, acc[r].y + bv.y,
                               acc[r].z + bv.z, acc[r].w + bv.w);
        ((float4*)(P + (size_t)gr * DIM))[tx] = o;
      }
    }
  }
}

// ---------------------------------------------------------------------------
// CSR build: histogram -> hierarchical scan (A/B/C) -> scatter
// ---------------------------------------------------------------------------
__global__ void hist_kernel(const int* __restrict__ recv, int* __restrict__ cnt,
                            int E) {
  int e = blockIdx.x * 256 + threadIdx.x;
  if (e < E) atomicAdd(&cnt[recv[e]], 1);
}

// inclusive scan of x across a 256-thread block (4 waves)
__device__ __forceinline__ int block_scan256(int x, int t, int* wsum) {
  const int lane = t & 63, wid = t >> 6;
  #pragma unroll
  for (int d = 1; d < 64; d <<= 1) {
    int y = __shfl_up(x, (unsigned)d);
    if (lane >= d) x += y;
  }
  if (lane == 63) wsum[wid] = x;
  __syncthreads();
  int add = 0;
  if (wid > 0) add += wsum[0];
  if (wid > 1) add += wsum[1];
  if (wid > 2) add += wsum[2];
  x += add;
  __syncthreads();  // wsum may be reused by caller loops
  return x;
}

// A: per-256-block inclusive scan of cnt -> offs[i+1] (partial), block sums
__global__ __launch_bounds__(256) void scanA_kernel(const int* __restrict__ cnt,
                                                    int* __restrict__ offs,
                                                    int* __restrict__ bsum,
                                                    int n) {
  __shared__ int wsum[4];
  const int t = threadIdx.x;
  const int i = blockIdx.x * 256 + t;
  int x = (i < n) ? cnt[i] : 0;
  int s = block_scan256(x, t, wsum);
  if (i < n) offs[i + 1] = s;
  if (t == 255) bsum[blockIdx.x] = s;
  if (t == 0 && blockIdx.x == 0) offs[0] = 0;
}

// B: single block scans the block sums -> exclusive bases
__global__ __launch_bounds__(256) void scanB_kernel(const int* __restrict__ bsum,
                                                    int* __restrict__ bbase,
                                                    int nb) {
  __shared__ int wsum[4];
  __shared__ int carry_s;
  const int t = threadIdx.x;
  if (t == 0) carry_s = 0;
  __syncthreads();
  for (int base = 0; base < nb; base += 256) {
    int i = base + t;
    int x = (i < nb) ? bsum[i] : 0;
    int s = block_scan256(x, t, wsum);
    int c = carry_s;
    if (i < nb) bbase[i] = c + s - x;  // exclusive base
    __syncthreads();
    if (t == 255) carry_s = c + s;     // s at t==255 == chunk total
    __syncthreads();
  }
}

// C: add block bases
__global__ __launch_bounds__(256) void scanC_kernel(int* __restrict__ offs,
                                                    const int* __restrict__ bbase,
                                                    int n) {
  const int i = blockIdx.x * 256 + threadIdx.x;
  if (i < n) offs[i + 1] += bbase[blockIdx.x];
}

__global__ void scatter_kernel(const int* __restrict__ recv,
                               const int* __restrict__ snd,
                               const int* __restrict__ offs,
                               int* __restrict__ cursor,
                               int* __restrict__ sorted_snd, int E) {
  int e = blockIdx.x * 256 + threadIdx.x;
  if (e < E) {
    int r = recv[e];
    int slot = offs[r] + atomicAdd(&cursor[r], 1);
    sorted_snd[slot] = snd[e];
  }
}

// ---------------------------------------------------------------------------
// Fused per-node kernel: one wave per receiver node.
// lane owns value-quad v = 4*lane..4*lane+3 (head h = lane/8).
// Online softmax across incoming edges; no atomics, no logits materialized.
// 1-deep software pipeline on the Pi gather.
// ---------------------------------------------------------------------------
__device__ __forceinline__ float mish_f(float x) {
  // mish(x) = x * tanh(softplus(x)) = x * u/(u+2), u = t(t+2), t = e^x
  float t = __expf(fminf(x, 40.f));
  float u = t * (t + 2.f);
  return x * u * __builtin_amdgcn_rcpf(u + 2.f);
}

__global__ __launch_bounds__(256) void node_kernel(
    const float* __restrict__ Pi, const float* __restrict__ Pj,
    const int* __restrict__ offs, const int* __restrict__ sorted_snd,
    const float* __restrict__ a_w, const float* __restrict__ a_b,
    float* __restrict__ out, int n) {
  const int wid = threadIdx.x >> 6, lane = threadIdx.x & 63;
  const int r = blockIdx.x * 4 + wid;
  if (r >= n) return;

  const int beg = offs[r], end = offs[r + 1];
  const float4* Pi4 = (const float4*)Pi;
  const float4* Pj4 = (const float4*)Pj;

  const float4 pj = Pj4[r * 64 + lane];
  const float4 aw = ((const float4*)a_w)[lane & 7];  // a_w index = (4*lane+i)%32
  const float ab = a_b[0];

  float4 acc = make_float4(0.f, 0.f, 0.f, 0.f);
  float m = -INFINITY, denom = 0.f;

  float4 pi_next = make_float4(0.f, 0.f, 0.f, 0.f);
  if (beg < end) pi_next = Pi4[(size_t)sorted_snd[beg] * 64 + lane];

  for (int idx = beg; idx < end; ++idx) {
    float4 pi = pi_next;
    if (idx + 1 < end)
      pi_next = Pi4[(size_t)sorted_snd[idx + 1] * 64 + lane];  // prefetch

    float partial;
    partial  = mish_f(pi.x + pj.x) * aw.x;
    partial += mish_f(pi.y + pj.y) * aw.y;
    partial += mish_f(pi.z + pj.z) * aw.z;
    partial += mish_f(pi.w + pj.w) * aw.w;
    // reduce over the 8 lanes sharing this head
    partial += __shfl_xor(partial, 1);
    partial += __shfl_xor(partial, 2);
    partial += __shfl_xor(partial, 4);

    float lo = partial + ab;
    float mn = fmaxf(m, lo);
    float scale = __expf(m - mn);            // first iter: exp(-inf)=0
    float p = __expf(lo - mn);
    denom = denom * scale + p;
    acc.x = acc.x * scale + p * pi.x;
    acc.y = acc.y * scale + p * pi.y;
    acc.z = acc.z * scale + p * pi.z;
    acc.w = acc.w * scale + p * pi.w;
    m = mn;
  }

  float inv = (end > beg) ? 1.f / denom : 0.f;
  float4 o = make_float4(acc.x * inv, acc.y * inv, acc.z * inv, acc.w * inv);
  ((float4*)out)[r * 64 + lane] = o;
}

// ---------------------------------------------------------------------------
extern "C" void kernel_launch(void* const* d_in, const int* in_sizes, int n_in,
                              void* d_out, int out_size, void* d_ws,
                              size_t ws_size, hipStream_t stream) {
  const float* nodes = (const float*)d_in[0];
  const int* senders = (const int*)d_in[1];
  const int* receivers = (const int*)d_in[2];
  const float* Wi = (const float*)d_in[3];
  const float* bi = (const float*)d_in[4];
  const float* Wj = (const float*)d_in[5];
  const float* bj = (const float*)d_in[6];
  const float* a_w = (const float*)d_in[7];
  const float* a_b = (const float*)d_in[8];
  float* out = (float*)d_out;

  const int N = in_sizes[0] / DIM;
  const int E = in_sizes[1];
  const int nb = (N + 255) / 256;  // scan blocks

  // workspace layout
  char* ws = (char*)d_ws;
  float* Pi = (float*)ws;                         // N*256 f32
  float* Pj = Pi + (size_t)N * DIM;               // N*256 f32
  int* cnt = (int*)(Pj + (size_t)N * DIM);        // N
  int* cursor = cnt + N;                          // N   (contiguous with cnt)
  int* offs = cursor + N;                         // N+1
  int* bsum = offs + N + 1;                       // nb
  int* bbase = bsum + nb;                         // nb
  int* sorted_snd = bbase + nb;                   // E

  // zero histogram + cursor in one memset
  hipMemsetAsync(cnt, 0, (size_t)2 * N * sizeof(int), stream);

  proj2_kernel<<<(N + 31) / 32, 256, 0, stream>>>(nodes, Wi, bi, Wj, bj, Pi,
                                                  Pj, N);

  hist_kernel<<<(E + 255) / 256, 256, 0, stream>>>(receivers, cnt, E);
  scanA_kernel<<<nb, 256, 0, stream>>>(cnt, offs, bsum, N);
  scanB_kernel<<<1, 256, 0, stream>>>(bsum, bbase, nb);
  scanC_kernel<<<nb, 256, 0, stream>>>(offs, bbase, N);
  scatter_kernel<<<(E + 255) / 256, 256, 0, stream>>>(receivers, senders, offs,
                                                      cursor, sorted_snd, E);

  node_kernel<<<(N + 3) / 4, 256, 0, stream>>>(Pi, Pj, offs, sorted_snd, a_w,
                                               a_b, out, N);
}